// Round 15
// baseline (26.703 us; speedup 1.0000x reference)
//
#include <hip/hip_runtime.h>
#include <hip/hip_bf16.h>

#define B_ROWS 32768
#define D_IN   128
#define H1_    256
#define HTAU   32
#define NBLK   128

#define NE     64
#define SMIN  (-8.0f)
#define SMAX  ( 8.0f)

typedef __bf16 bf16_t;
typedef bf16_t bf16x8 __attribute__((ext_vector_type(8)));
typedef float  f32x4  __attribute__((ext_vector_type(4)));

__device__ __forceinline__ bf16x8 cvt8(const float* v) {
    bf16x8 r;
#pragma unroll
    for (int i = 0; i < 8; ++i) r[i] = (bf16_t)v[i];
    return r;
}

// async global->LDS, 16B/lane; LDS dest = wave-uniform base + lane*16
__device__ __forceinline__ void gload_lds16(const void* g, void* l) {
    __builtin_amdgcn_global_load_lds(
        (const __attribute__((address_space(1))) uint32_t*)g,
        (__attribute__((address_space(3))) uint32_t*)l, 16, 0, 0);
}

// ---------------------------------------------------------------------------
// prep: blocks [0,128): tau table pairs; blocks [128,176): W -> bf16 frag order
// ---------------------------------------------------------------------------
__global__ void prep(const float* __restrict__ w1, const float* __restrict__ w2,
                     const float* __restrict__ wt1, const float* __restrict__ bt1,
                     const float* __restrict__ wt2, const float* __restrict__ bt2,
                     float2* __restrict__ tab2,
                     bf16x8* __restrict__ w1f, bf16x8* __restrict__ w2f) {
    __shared__ float ps[4][64];
    const int bid = blockIdx.x, tid = threadIdx.x;
    if (bid < NBLK) {
        const int n  = bid;
        const int e  = tid & 63;
        const int hh = tid >> 6;
        float s = SMIN + (SMAX - SMIN) * (float)e / (float)(NE - 1);
        float part = (hh == 0) ? bt2[n] : 0.f;
#pragma unroll
        for (int j = 0; j < 8; ++j) {
            int h = hh * 8 + j;
            float z  = s * wt1[n * HTAU + h] + bt1[n * HTAU + h];
            float sp = (z > 20.f) ? z : log1pf(expf(z));
            part += wt2[n * HTAU + h] * sp;
        }
        ps[hh][e] = part;
        __syncthreads();
        if (hh == 0) {
            float acc = ps[0][e] + ps[1][e] + ps[2][e] + ps[3][e];
            float nxt = __shfl_down(acc, 1, 64);
            tab2[n * NE + e] = make_float2(acc, nxt);
        }
    } else {
        const int cid  = (bid - NBLK) * 256 + tid;
        const int isW2 = cid >= 4096;
        const int c2   = isW2 ? cid - 4096 : cid;
        const int kk = c2 >> 10, c = c2 & 1023;
        const int nf = c >> 6,  ll = c & 63;
        const int col = nf * 16 + (ll & 15);
        const int kr  = kk * 32 + (ll >> 4) * 8;
        const float* src = isW2 ? (w2 + col * H1_ + kr) : (w1 + col * D_IN + kr);
        float tmp[8];
        *(f32x4*)tmp       = *(const f32x4*)src;
        *(f32x4*)(tmp + 4) = *(const f32x4*)(src + 4);
        (isW2 ? w2f : w1f)[c2] = cvt8(tmp);
    }
}

// ---------------------------------------------------------------------------
// fused_main r15: B-fragment reuse (2 row-groups per wave) to halve LDS reads.
// BM=128, 512 thr (8 waves). Wave w: rows (w&3)*32..+31 (2 x 16-row groups),
// cols (w>>2)*128..+127 (8 nf frags). Each B ds_read feeds 2 MFMAs ->
// per-step LDS traffic 144KB -> 80KB/CU (the r13/r14 nulls' explanation).
// Same 4-buffer / vmcnt(4) / 1-barrier pipeline as r14. h1 is cross-wave
// (col halves): lgkmcnt(0)+sched_barrier fence after h1 write (r13-proven).
// tau: A-frag x registers reused; 4 q-lanes per row hold all 128 cols.
// LDS = 64KB wsl + 64KB h1 = 128KB, 1 wg/CU (8 waves, 2/SIMD).
// ---------------------------------------------------------------------------
__global__ __launch_bounds__(512, 2)
void fused_main(const float* __restrict__ x,
                const bf16x8* __restrict__ w1f, const bf16x8* __restrict__ w2f,
                const float* __restrict__ b1, const float* __restrict__ b2,
                const float* __restrict__ w3, const float* __restrict__ b3,
                const float2* __restrict__ tab2, const float* __restrict__ wlr,
                const float* __restrict__ blr,
                float* __restrict__ mu_out, float* __restrict__ lr_out) {
    __shared__ bf16x8 wsl[4096];          // 4 x 16KB rotating W slices
    __shared__ char   h1_raw[128 * 512];  // 64KB bf16 [128][256], swizzled

    const int tid = threadIdx.x;
    const int l   = tid & 63;
    const int w   = tid >> 6;             // wave 0..7
    const int wq  = w & 3;                // row block: rows wq*32..+31
    const int wh  = w >> 2;               // column half
    const int q   = l >> 4;
    const int l15 = l & 15;
    const int rb  = blockIdx.x * 128;

    // stage slice i (i<4: W1 kk=i; else W2 kk=i-4) into buffer (i&3)
    auto STAGE = [&](int i) {
        const bf16x8* src = (i < 4) ? (w1f + i * 1024) : (w2f + (i - 4) * 1024);
        bf16x8* dst = wsl + (i & 3) * 1024 + w * 64;
        gload_lds16(src + w * 64 + l,       dst);
        gload_lds16(src + w * 64 + 512 + l, dst + 512);
    };

    STAGE(0);
    STAGE(1);

    // ---- prologue: x rows for both groups -> a1; tau on col-half 0 ----
    float tsum[2] = {0.f, 0.f};
    bf16x8 a1[2][4];
    {
        const float INVDS = (float)(NE - 1) / (SMAX - SMIN);
#pragma unroll
        for (int g = 0; g < 2; ++g) {
            const int rg = wq * 32 + g * 16 + l15;
            const float* xr = x + (size_t)(rb + rg) * D_IN + q * 8;
#pragma unroll
            for (int kk = 0; kk < 4; ++kk) {
                float t[8];
                *(f32x4*)t     = *(const f32x4*)(xr + kk * 32);
                *(f32x4*)(t+4) = *(const f32x4*)(xr + kk * 32 + 4);
                a1[g][kk] = cvt8(t);
                if (wh == 0) {
                    float wv[8];
                    *(f32x4*)wv     = *(const f32x4*)(wlr + q * 8 + kk * 32);
                    *(f32x4*)(wv+4) = *(const f32x4*)(wlr + q * 8 + kk * 32 + 4);
#pragma unroll
                    for (int i = 0; i < 8; ++i) {
                        float s = fminf(fmaxf(t[i], SMIN), SMAX);
                        float u = (s - SMIN) * INVDS;
                        int ii = (int)u;
                        ii = ii > NE - 2 ? NE - 2 : ii;
                        float fr = u - (float)ii;
                        int n = kk * 32 + q * 8 + i;
                        float2 tv = tab2[n * NE + ii];
                        tsum[g] += wv[i] * (tv.x + (tv.y - tv.x) * fr);
                    }
                }
            }
        }
        if (wh == 0) {
#pragma unroll
            for (int g = 0; g < 2; ++g) {
                tsum[g] += __shfl_xor(tsum[g], 16, 64);
                tsum[g] += __shfl_xor(tsum[g], 32, 64);
            }
        }
    }
    STAGE(2);   // issued after tau so its loads aren't drained by tau's waits

    f32x4 acc[2][8];
#pragma unroll
    for (int g = 0; g < 2; ++g)
#pragma unroll
        for (int f = 0; f < 8; ++f) acc[g][f] = (f32x4){0.f, 0.f, 0.f, 0.f};

    // ---- 12-step pipelined K loop (steps 0-3: layer 1; 4-11: layer 2) ----
#pragma unroll
    for (int s = 0; s < 12; ++s) {
        asm volatile("s_waitcnt vmcnt(4)" ::: "memory");  // slice s landed
        __builtin_amdgcn_sched_barrier(0);
        __builtin_amdgcn_s_barrier();
        const bf16x8* wb = wsl + (s & 3) * 1024 + (wh * 8) * 64;  // our 8 frags

        if (s < 4) {
#pragma unroll
            for (int f = 0; f < 8; ++f) {
                bf16x8 b = wb[f * 64 + l];
#pragma unroll
                for (int g = 0; g < 2; ++g)
                    acc[g][f] = __builtin_amdgcn_mfma_f32_16x16x32_bf16(
                        a1[g][s], b, acc[g][f], 0, 0, 0);
            }
            if (s == 3) {   // h1 = relu(acc+b1) -> LDS (cross-wave col halves)
#pragma unroll
                for (int g = 0; g < 2; ++g)
#pragma unroll
                    for (int f = 0; f < 8; ++f) {
                        int col = wh * 128 + f * 16 + l15;
                        float bias = b1[col];
#pragma unroll
                        for (int r = 0; r < 4; ++r) {
                            int gr = wq * 32 + g * 16 + q * 4 + r;
                            float v = acc[g][f][r] + bias;
                            v = v > 0.f ? v : 0.f;
                            int byte = (gr * 512 + col * 2) ^ ((gr & 7) << 4);
                            *(bf16_t*)(h1_raw + byte) = (bf16_t)v;
                        }
                        acc[g][f] = (f32x4){0.f, 0.f, 0.f, 0.f};
                    }
                asm volatile("s_waitcnt lgkmcnt(0)" ::: "memory");
                __builtin_amdgcn_sched_barrier(0);
            }
        } else {
#pragma unroll
            for (int g = 0; g < 2; ++g) {
                int rg   = wq * 32 + g * 16 + l15;
                int k0   = (s - 4) * 32 + q * 8;
                int byte = (rg * 512 + k0 * 2) ^ ((rg & 7) << 4);
                bf16x8 a = *(bf16x8*)(h1_raw + byte);
#pragma unroll
                for (int f = 0; f < 8; ++f)
                    acc[g][f] = __builtin_amdgcn_mfma_f32_16x16x32_bf16(
                        a, wb[f * 64 + l], acc[g][f], 0, 0, 0);
            }
        }

        if (s < 9) STAGE(s + 3);          // refill buf((s+3)&3): safe post-MFMA
    }

    // ---- epilogue: mu = relu(acc + b2) . w3 + b3, cross-half reduce ----
    float p[2][4] = {{0.f,0.f,0.f,0.f},{0.f,0.f,0.f,0.f}};
#pragma unroll
    for (int g = 0; g < 2; ++g)
#pragma unroll
        for (int f = 0; f < 8; ++f) {
            int col = wh * 128 + f * 16 + l15;
            float bias = b2[col];
            float wv   = w3[col];
#pragma unroll
            for (int r = 0; r < 4; ++r) {
                float v = acc[g][f][r] + bias;
                v = v > 0.f ? v : 0.f;
                p[g][r] += v * wv;
            }
        }
#pragma unroll
    for (int m = 1; m < 16; m <<= 1)
#pragma unroll
        for (int g = 0; g < 2; ++g)
#pragma unroll
            for (int r = 0; r < 4; ++r) p[g][r] += __shfl_xor(p[g][r], m, 64);

    // h1 LDS free only after ALL waves' layer-2 reads
    asm volatile("s_waitcnt lgkmcnt(0)" ::: "memory");
    __builtin_amdgcn_s_barrier();
    float* mu_p = (float*)h1_raw;        // reuse 512B of h1 space
    if (wh == 0 && l15 == 0) {
#pragma unroll
        for (int g = 0; g < 2; ++g)
#pragma unroll
            for (int r = 0; r < 4; ++r)
                mu_p[wq * 32 + g * 16 + q * 4 + r] = p[g][r];
    }
    __syncthreads();
    if (wh == 1 && l15 == 0) {
        float bb = b3[0];
#pragma unroll
        for (int g = 0; g < 2; ++g)
#pragma unroll
            for (int r = 0; r < 4; ++r) {
                int gr = wq * 32 + g * 16 + q * 4 + r;
                mu_out[rb + gr] = mu_p[gr] + p[g][r] + bb;
            }
    }
    // deferred tau store
    if (wh == 0 && q == 0) {
#pragma unroll
        for (int g = 0; g < 2; ++g)
            lr_out[rb + wq * 32 + g * 16 + l15] = tsum[g] + blr[0];
    }
}

extern "C" void kernel_launch(void* const* d_in, const int* in_sizes, int n_in,
                              void* d_out, int out_size, void* d_ws, size_t ws_size,
                              hipStream_t stream) {
    const float* x   = (const float*)d_in[0];
    const float* w1  = (const float*)d_in[1];
    const float* b1  = (const float*)d_in[2];
    const float* w2  = (const float*)d_in[3];
    const float* b2  = (const float*)d_in[4];
    const float* w3  = (const float*)d_in[5];
    const float* b3  = (const float*)d_in[6];
    const float* wt1 = (const float*)d_in[7];
    const float* bt1 = (const float*)d_in[8];
    const float* wt2 = (const float*)d_in[9];
    const float* bt2 = (const float*)d_in[10];
    const float* wlr = (const float*)d_in[11];
    const float* blr = (const float*)d_in[12];

    float* out    = (float*)d_out;
    float* mu_out = out;                 // output 0: mu     [32768]
    float* lr_out = out + B_ROWS;        // output 1: out_lr [32768]

    char* ws = (char*)d_ws;
    float2* tab2 = (float2*)ws;                   // 64KB
    bf16x8* w1f  = (bf16x8*)(ws + (64 << 10));    // 64KB
    bf16x8* w2f  = (bf16x8*)(ws + (128 << 10));   // 128KB

    prep<<<NBLK + 48, 256, 0, stream>>>(w1, w2, wt1, bt1, wt2, bt2, tab2, w1f, w2f);
    fused_main<<<B_ROWS / 128, 512, 0, stream>>>(x, w1f, w2f, b1, b2, w3, b3,
                                                 tab2, wlr, blr, mu_out, lr_out);
}

// Round 16
// 24.398 us; speedup vs baseline: 1.0945x; 1.0945x over previous
//
#include <hip/hip_runtime.h>
#include <hip/hip_bf16.h>

#define B_ROWS 32768
#define D_IN   128
#define H1_    256
#define HTAU   32
#define NBLK   128

#define NE     64
#define SMIN  (-8.0f)
#define SMAX  ( 8.0f)

typedef __bf16 bf16_t;
typedef bf16_t bf16x8 __attribute__((ext_vector_type(8)));
typedef float  f32x4  __attribute__((ext_vector_type(4)));

__device__ __forceinline__ bf16x8 cvt8(const float* v) {
    bf16x8 r;
#pragma unroll
    for (int i = 0; i < 8; ++i) r[i] = (bf16_t)v[i];
    return r;
}

// async global->LDS, 16B/lane; LDS dest = wave-uniform base + lane*16
__device__ __forceinline__ void gload_lds16(const void* g, void* l) {
    __builtin_amdgcn_global_load_lds(
        (const __attribute__((address_space(1))) uint32_t*)g,
        (__attribute__((address_space(3))) uint32_t*)l, 16, 0, 0);
}

// ---------------------------------------------------------------------------
// prep: blocks [0,128): tau table pairs; blocks [128,176): W -> bf16 frag order
// ---------------------------------------------------------------------------
__global__ void prep(const float* __restrict__ w1, const float* __restrict__ w2,
                     const float* __restrict__ wt1, const float* __restrict__ bt1,
                     const float* __restrict__ wt2, const float* __restrict__ bt2,
                     float2* __restrict__ tab2,
                     bf16x8* __restrict__ w1f, bf16x8* __restrict__ w2f) {
    __shared__ float ps[4][64];
    const int bid = blockIdx.x, tid = threadIdx.x;
    if (bid < NBLK) {
        const int n  = bid;
        const int e  = tid & 63;
        const int hh = tid >> 6;
        float s = SMIN + (SMAX - SMIN) * (float)e / (float)(NE - 1);
        float part = (hh == 0) ? bt2[n] : 0.f;
#pragma unroll
        for (int j = 0; j < 8; ++j) {
            int h = hh * 8 + j;
            float z  = s * wt1[n * HTAU + h] + bt1[n * HTAU + h];
            float sp = (z > 20.f) ? z : log1pf(expf(z));
            part += wt2[n * HTAU + h] * sp;
        }
        ps[hh][e] = part;
        __syncthreads();
        if (hh == 0) {
            float acc = ps[0][e] + ps[1][e] + ps[2][e] + ps[3][e];
            float nxt = __shfl_down(acc, 1, 64);
            tab2[n * NE + e] = make_float2(acc, nxt);
        }
    } else {
        const int cid  = (bid - NBLK) * 256 + tid;
        const int isW2 = cid >= 4096;
        const int c2   = isW2 ? cid - 4096 : cid;
        const int kk = c2 >> 10, c = c2 & 1023;
        const int nf = c >> 6,  ll = c & 63;
        const int col = nf * 16 + (ll & 15);
        const int kr  = kk * 32 + (ll >> 4) * 8;
        const float* src = isW2 ? (w2 + col * H1_ + kr) : (w1 + col * D_IN + kr);
        float tmp[8];
        *(f32x4*)tmp       = *(const f32x4*)src;
        *(f32x4*)(tmp + 4) = *(const f32x4*)(src + 4);
        (isW2 ? w2f : w1f)[c2] = cvt8(tmp);
    }
}

// ---------------------------------------------------------------------------
// fused_main (r14 revert, best known: 24.16us): BM=128, 4-buffer 2-deep
// counted-vmcnt pipeline, wave-private h1 rows, one s_barrier per step.
// 512 thr (8 waves), each wave = 16 rows x 256 cols (acc[16]).
// Prologue stages slices 0,1,2; step s: vmcnt(4) -> barrier -> MFMA buf(s&3)
// -> STAGE(s+3) into buf((s-1)&3) (last read step s-1, safe past barrier(s)).
// LDS = 64KB wsl + 64KB h1 = 128KB, 1 wg/CU.
// ---------------------------------------------------------------------------
__global__ __launch_bounds__(512, 2)
void fused_main(const float* __restrict__ x,
                const bf16x8* __restrict__ w1f, const bf16x8* __restrict__ w2f,
                const float* __restrict__ b1, const float* __restrict__ b2,
                const float* __restrict__ w3, const float* __restrict__ b3,
                const float2* __restrict__ tab2, const float* __restrict__ wlr,
                const float* __restrict__ blr,
                float* __restrict__ mu_out, float* __restrict__ lr_out) {
    __shared__ bf16x8 wsl[4096];          // 4 x 16KB rotating W slices
    __shared__ char   h1_raw[128 * 512];  // 64KB bf16 [128][256], swizzled

    const int tid = threadIdx.x;
    const int l   = tid & 63;
    const int w   = tid >> 6;             // wave 0..7
    const int q   = l >> 4;
    const int l15 = l & 15;
    const int row = w * 16 + l15;         // block-local row 0..127
    const int rb  = blockIdx.x * 128;

    // stage slice i (i<4: W1 kk=i; else W2 kk=i-4) into buffer (i&3)
    auto STAGE = [&](int i) {
        const bf16x8* src = (i < 4) ? (w1f + i * 1024) : (w2f + (i - 4) * 1024);
        bf16x8* dst = wsl + (i & 3) * 1024 + w * 64;
        gload_lds16(src + w * 64 + l,       dst);
        gload_lds16(src + w * 64 + 512 + l, dst + 512);
    };

    // ---- prologue: issue slices 0,1,2; x + tau (all 8 waves, 1 row/lane) ----
    STAGE(0);
    STAGE(1);
    STAGE(2);

    float tsum = 0.f;
    bf16x8 a1[4];
    {
        const float* xr = x + (size_t)(rb + row) * D_IN + q * 8;
        const float* wr = wlr + q * 8;
        const float INVDS = (float)(NE - 1) / (SMAX - SMIN);
#pragma unroll
        for (int kk = 0; kk < 4; ++kk) {
            float t[8], wv[8];
            *(f32x4*)t      = *(const f32x4*)(xr + kk * 32);
            *(f32x4*)(t+4)  = *(const f32x4*)(xr + kk * 32 + 4);
            *(f32x4*)wv     = *(const f32x4*)(wr + kk * 32);
            *(f32x4*)(wv+4) = *(const f32x4*)(wr + kk * 32 + 4);
            a1[kk] = cvt8(t);
#pragma unroll
            for (int i = 0; i < 8; ++i) {
                float s = fminf(fmaxf(t[i], SMIN), SMAX);
                float u = (s - SMIN) * INVDS;
                int ii = (int)u;
                ii = ii > NE - 2 ? NE - 2 : ii;
                float fr = u - (float)ii;
                int n = kk * 32 + q * 8 + i;
                float2 tv = tab2[n * NE + ii];
                tsum += wv[i] * (tv.x + (tv.y - tv.x) * fr);
            }
        }
        tsum += __shfl_xor(tsum, 16, 64);
        tsum += __shfl_xor(tsum, 32, 64);
    }

    f32x4 acc[16];
#pragma unroll
    for (int f = 0; f < 16; ++f) acc[f] = (f32x4){0.f, 0.f, 0.f, 0.f};

    // ---- 12-step pipelined K loop (steps 0-3: layer 1; 4-11: layer 2) ----
#pragma unroll
    for (int s = 0; s < 12; ++s) {
        asm volatile("s_waitcnt vmcnt(4)" ::: "memory");  // slice s landed
        __builtin_amdgcn_sched_barrier(0);
        __builtin_amdgcn_s_barrier();                     // all waves' portions
        const bf16x8* wb = wsl + (s & 3) * 1024;

        if (s < 4) {
#pragma unroll
            for (int nf = 0; nf < 16; ++nf)
                acc[nf] = __builtin_amdgcn_mfma_f32_16x16x32_bf16(
                    a1[s], wb[nf * 64 + l], acc[nf], 0, 0, 0);
            if (s == 3) {   // h1 = relu(acc+b1) -> LDS (wave-private rows)
#pragma unroll
                for (int f = 0; f < 16; ++f) {
                    int col = f * 16 + l15;
                    float bias = b1[col];
#pragma unroll
                    for (int r = 0; r < 4; ++r) {
                        int gr = w * 16 + q * 4 + r;
                        float v = acc[f][r] + bias;
                        v = v > 0.f ? v : 0.f;
                        int byte = (gr * 512 + col * 2) ^ ((gr & 7) << 4);
                        *(bf16_t*)(h1_raw + byte) = (bf16_t)v;
                    }
                    acc[f] = (f32x4){0.f, 0.f, 0.f, 0.f};
                }
            }
        } else {
            int k0   = (s - 4) * 32 + q * 8;
            int byte = (row * 512 + k0 * 2) ^ ((row & 7) << 4);
            bf16x8 a = *(bf16x8*)(h1_raw + byte);
#pragma unroll
            for (int nf = 0; nf < 16; ++nf)
                acc[nf] = __builtin_amdgcn_mfma_f32_16x16x32_bf16(
                    a, wb[nf * 64 + l], acc[nf], 0, 0, 0);
        }

        if (s < 9) STAGE(s + 3);          // refill buf((s+3)&3): safe post-MFMA
    }

    // ---- epilogue: mu = relu(acc + b2) . w3 + b3 (per-wave, full cols) ----
    float p[4] = {0.f, 0.f, 0.f, 0.f};
#pragma unroll
    for (int f = 0; f < 16; ++f) {
        int col = f * 16 + l15;
        float bias = b2[col];
        float wv   = w3[col];
#pragma unroll
        for (int r = 0; r < 4; ++r) {
            float v = acc[f][r] + bias;
            v = v > 0.f ? v : 0.f;
            p[r] += v * wv;
        }
    }
#pragma unroll
    for (int m = 1; m < 16; m <<= 1) {
#pragma unroll
        for (int r = 0; r < 4; ++r) p[r] += __shfl_xor(p[r], m, 64);
    }
    if (l15 == 0) {
        float bb = b3[0];
#pragma unroll
        for (int r = 0; r < 4; ++r)
            mu_out[rb + w * 16 + q * 4 + r] = p[r] + bb;
    }
    // deferred tau store (barrier-free tail)
    if (q == 0) lr_out[rb + row] = tsum + blr[0];
}

extern "C" void kernel_launch(void* const* d_in, const int* in_sizes, int n_in,
                              void* d_out, int out_size, void* d_ws, size_t ws_size,
                              hipStream_t stream) {
    const float* x   = (const float*)d_in[0];
    const float* w1  = (const float*)d_in[1];
    const float* b1  = (const float*)d_in[2];
    const float* w2  = (const float*)d_in[3];
    const float* b2  = (const float*)d_in[4];
    const float* w3  = (const float*)d_in[5];
    const float* b3  = (const float*)d_in[6];
    const float* wt1 = (const float*)d_in[7];
    const float* bt1 = (const float*)d_in[8];
    const float* wt2 = (const float*)d_in[9];
    const float* bt2 = (const float*)d_in[10];
    const float* wlr = (const float*)d_in[11];
    const float* blr = (const float*)d_in[12];

    float* out    = (float*)d_out;
    float* mu_out = out;                 // output 0: mu     [32768]
    float* lr_out = out + B_ROWS;        // output 1: out_lr [32768]

    char* ws = (char*)d_ws;
    float2* tab2 = (float2*)ws;                   // 64KB
    bf16x8* w1f  = (bf16x8*)(ws + (64 << 10));    // 64KB
    bf16x8* w2f  = (bf16x8*)(ws + (128 << 10));   // 128KB

    prep<<<NBLK + 48, 256, 0, stream>>>(w1, w2, wt1, bt1, wt2, bt2, tab2, w1f, w2f);
    fused_main<<<B_ROWS / 128, 512, 0, stream>>>(x, w1f, w2f, b1, b2, w3, b3,
                                                 tab2, wlr, blr, mu_out, lr_out);
}

// Round 17
// 23.781 us; speedup vs baseline: 1.1228x; 1.0259x over previous
//
#include <hip/hip_runtime.h>
#include <hip/hip_bf16.h>

#define B_ROWS 32768
#define D_IN   128
#define H1_    256
#define HTAU   32
#define NBLK   128

#define NE     64
#define SMIN  (-8.0f)
#define SMAX  ( 8.0f)

typedef __bf16 bf16_t;
typedef bf16_t bf16x8 __attribute__((ext_vector_type(8)));
typedef float  f32x4  __attribute__((ext_vector_type(4)));

__device__ __forceinline__ bf16x8 cvt8(const float* v) {
    bf16x8 r;
#pragma unroll
    for (int i = 0; i < 8; ++i) r[i] = (bf16_t)v[i];
    return r;
}

// async global->LDS, 16B/lane; LDS dest = wave-uniform base + lane*16
__device__ __forceinline__ void gload_lds16(const void* g, void* l) {
    __builtin_amdgcn_global_load_lds(
        (const __attribute__((address_space(1))) uint32_t*)g,
        (__attribute__((address_space(3))) uint32_t*)l, 16, 0, 0);
}

// ---------------------------------------------------------------------------
// prep: blocks [0,128): tau table pairs; blocks [128,176): W -> bf16 frag order
// ---------------------------------------------------------------------------
__global__ void prep(const float* __restrict__ w1, const float* __restrict__ w2,
                     const float* __restrict__ wt1, const float* __restrict__ bt1,
                     const float* __restrict__ wt2, const float* __restrict__ bt2,
                     float2* __restrict__ tab2,
                     bf16x8* __restrict__ w1f, bf16x8* __restrict__ w2f) {
    __shared__ float ps[4][64];
    const int bid = blockIdx.x, tid = threadIdx.x;
    if (bid < NBLK) {
        const int n  = bid;
        const int e  = tid & 63;
        const int hh = tid >> 6;
        float s = SMIN + (SMAX - SMIN) * (float)e / (float)(NE - 1);
        float part = (hh == 0) ? bt2[n] : 0.f;
#pragma unroll
        for (int j = 0; j < 8; ++j) {
            int h = hh * 8 + j;
            float z  = s * wt1[n * HTAU + h] + bt1[n * HTAU + h];
            float sp = (z > 20.f) ? z : log1pf(expf(z));
            part += wt2[n * HTAU + h] * sp;
        }
        ps[hh][e] = part;
        __syncthreads();
        if (hh == 0) {
            float acc = ps[0][e] + ps[1][e] + ps[2][e] + ps[3][e];
            float nxt = __shfl_down(acc, 1, 64);
            tab2[n * NE + e] = make_float2(acc, nxt);
        }
    } else {
        const int cid  = (bid - NBLK) * 256 + tid;
        const int isW2 = cid >= 4096;
        const int c2   = isW2 ? cid - 4096 : cid;
        const int kk = c2 >> 10, c = c2 & 1023;
        const int nf = c >> 6,  ll = c & 63;
        const int col = nf * 16 + (ll & 15);
        const int kr  = kk * 32 + (ll >> 4) * 8;
        const float* src = isW2 ? (w2 + col * H1_ + kr) : (w1 + col * D_IN + kr);
        float tmp[8];
        *(f32x4*)tmp       = *(const f32x4*)src;
        *(f32x4*)(tmp + 4) = *(const f32x4*)(src + 4);
        (isW2 ? w2f : w1f)[c2] = cvt8(tmp);
    }
}

// ---------------------------------------------------------------------------
// fused_main r17: r14 pipeline with K-64 steps -> 6 barrier joins (was 12).
// BM=128, 512 thr (8 waves), each wave 16 rows x 256 cols, acc[16],
// wave-private h1 rows. 3 rotating 32KB pair-buffers (pairs of K-32 slices):
//   prologue: STAGE_PAIR(0), STAGE_PAIR(1) (drained early by tau's in-order
//   vmcnt waits on the x/tab loads issued after them);
//   step s (0..5): vmcnt(4) [retires pair s; pair s+1 stays in flight;
//   s==5 uses vmcnt(0) -- its pair was issued 2 steps back, drain is free
//   but formally required] -> s_barrier -> 32 MFMA from buf(s%3) ->
//   STAGE_PAIR(s+2) into buf((s+2)%3) (last read step s-1, safe).
// Steps 0,1 = layer 1 (h1 epilogue at s==1); steps 2..5 = layer 2.
// LDS = 96KB wsl + 64KB h1 = 160KB (full CU pool), 1 wg/CU, grid 256.
// ---------------------------------------------------------------------------
__global__ __launch_bounds__(512, 2)
void fused_main(const float* __restrict__ x,
                const bf16x8* __restrict__ w1f, const bf16x8* __restrict__ w2f,
                const float* __restrict__ b1, const float* __restrict__ b2,
                const float* __restrict__ w3, const float* __restrict__ b3,
                const float2* __restrict__ tab2, const float* __restrict__ wlr,
                const float* __restrict__ blr,
                float* __restrict__ mu_out, float* __restrict__ lr_out) {
    __shared__ bf16x8 wsl[6144];          // 3 x 32KB rotating W pair-slices
    __shared__ char   h1_raw[128 * 512];  // 64KB bf16 [128][256], swizzled

    const int tid = threadIdx.x;
    const int l   = tid & 63;
    const int w   = tid >> 6;             // wave 0..7
    const int q   = l >> 4;
    const int l15 = l & 15;
    const int row = w * 16 + l15;         // block-local row 0..127
    const int rb  = blockIdx.x * 128;

    // stage pair p (slices 2p,2p+1; p<2: W1, else W2) into buffer (p%3)
    auto STAGE = [&](int p) {
        const bf16x8* src = (p < 2) ? (w1f + p * 2048) : (w2f + (p - 2) * 2048);
        bf16x8* dst = wsl + (p % 3) * 2048 + w * 256;
#pragma unroll
        for (int j = 0; j < 4; ++j)
            gload_lds16(src + w * 256 + j * 64 + l, dst + j * 64);
    };

    // ---- prologue: issue pairs 0,1; x + tau (all 8 waves, 1 row/lane) ----
    STAGE(0);
    STAGE(1);

    float tsum = 0.f;
    bf16x8 a1[4];
    {
        const float* xr = x + (size_t)(rb + row) * D_IN + q * 8;
        const float* wr = wlr + q * 8;
        const float INVDS = (float)(NE - 1) / (SMAX - SMIN);
#pragma unroll
        for (int kk = 0; kk < 4; ++kk) {
            float t[8], wv[8];
            *(f32x4*)t      = *(const f32x4*)(xr + kk * 32);
            *(f32x4*)(t+4)  = *(const f32x4*)(xr + kk * 32 + 4);
            *(f32x4*)wv     = *(const f32x4*)(wr + kk * 32);
            *(f32x4*)(wv+4) = *(const f32x4*)(wr + kk * 32 + 4);
            a1[kk] = cvt8(t);
#pragma unroll
            for (int i = 0; i < 8; ++i) {
                float s = fminf(fmaxf(t[i], SMIN), SMAX);
                float u = (s - SMIN) * INVDS;
                int ii = (int)u;
                ii = ii > NE - 2 ? NE - 2 : ii;
                float fr = u - (float)ii;
                int n = kk * 32 + q * 8 + i;
                float2 tv = tab2[n * NE + ii];
                tsum += wv[i] * (tv.x + (tv.y - tv.x) * fr);
            }
        }
        tsum += __shfl_xor(tsum, 16, 64);
        tsum += __shfl_xor(tsum, 32, 64);
    }

    f32x4 acc[16];
#pragma unroll
    for (int f = 0; f < 16; ++f) acc[f] = (f32x4){0.f, 0.f, 0.f, 0.f};

    // ---- 6-step pipelined K loop (steps 0,1: layer 1; 2..5: layer 2) ----
#pragma unroll
    for (int s = 0; s < 6; ++s) {
        if (s < 5) {
            asm volatile("s_waitcnt vmcnt(4)" ::: "memory");  // pair s landed
        } else {
            asm volatile("s_waitcnt vmcnt(0)" ::: "memory");  // final drain
        }
        __builtin_amdgcn_sched_barrier(0);
        __builtin_amdgcn_s_barrier();                     // all waves' portions
        const bf16x8* wb = wsl + (s % 3) * 2048;

        if (s < 2) {
#pragma unroll
            for (int kh = 0; kh < 2; ++kh)
#pragma unroll
                for (int nf = 0; nf < 16; ++nf)
                    acc[nf] = __builtin_amdgcn_mfma_f32_16x16x32_bf16(
                        a1[s * 2 + kh], wb[kh * 1024 + nf * 64 + l], acc[nf], 0, 0, 0);
            if (s == 1) {   // h1 = relu(acc+b1) -> LDS (wave-private rows)
#pragma unroll
                for (int f = 0; f < 16; ++f) {
                    int col = f * 16 + l15;
                    float bias = b1[col];
#pragma unroll
                    for (int r = 0; r < 4; ++r) {
                        int gr = w * 16 + q * 4 + r;
                        float v = acc[f][r] + bias;
                        v = v > 0.f ? v : 0.f;
                        int byte = (gr * 512 + col * 2) ^ ((gr & 7) << 4);
                        *(bf16_t*)(h1_raw + byte) = (bf16_t)v;
                    }
                    acc[f] = (f32x4){0.f, 0.f, 0.f, 0.f};
                }
            }
        } else {
#pragma unroll
            for (int kh = 0; kh < 2; ++kh) {
                int k0   = ((s - 2) * 2 + kh) * 32 + q * 8;
                int byte = (row * 512 + k0 * 2) ^ ((row & 7) << 4);
                bf16x8 a = *(bf16x8*)(h1_raw + byte);
#pragma unroll
                for (int nf = 0; nf < 16; ++nf)
                    acc[nf] = __builtin_amdgcn_mfma_f32_16x16x32_bf16(
                        a, wb[kh * 1024 + nf * 64 + l], acc[nf], 0, 0, 0);
            }
        }

        if (s < 4) STAGE(s + 2);          // refill buf((s+2)%3): safe post-MFMA
    }

    // ---- epilogue: mu = relu(acc + b2) . w3 + b3 (per-wave, full cols) ----
    float p[4] = {0.f, 0.f, 0.f, 0.f};
#pragma unroll
    for (int f = 0; f < 16; ++f) {
        int col = f * 16 + l15;
        float bias = b2[col];
        float wv   = w3[col];
#pragma unroll
        for (int r = 0; r < 4; ++r) {
            float v = acc[f][r] + bias;
            v = v > 0.f ? v : 0.f;
            p[r] += v * wv;
        }
    }
#pragma unroll
    for (int m = 1; m < 16; m <<= 1) {
#pragma unroll
        for (int r = 0; r < 4; ++r) p[r] += __shfl_xor(p[r], m, 64);
    }
    if (l15 == 0) {
        float bb = b3[0];
#pragma unroll
        for (int r = 0; r < 4; ++r)
            mu_out[rb + w * 16 + q * 4 + r] = p[r] + bb;
    }
    // deferred tau store (barrier-free tail)
    if (q == 0) lr_out[rb + row] = tsum + blr[0];
}

extern "C" void kernel_launch(void* const* d_in, const int* in_sizes, int n_in,
                              void* d_out, int out_size, void* d_ws, size_t ws_size,
                              hipStream_t stream) {
    const float* x   = (const float*)d_in[0];
    const float* w1  = (const float*)d_in[1];
    const float* b1  = (const float*)d_in[2];
    const float* w2  = (const float*)d_in[3];
    const float* b2  = (const float*)d_in[4];
    const float* w3  = (const float*)d_in[5];
    const float* b3  = (const float*)d_in[6];
    const float* wt1 = (const float*)d_in[7];
    const float* bt1 = (const float*)d_in[8];
    const float* wt2 = (const float*)d_in[9];
    const float* bt2 = (const float*)d_in[10];
    const float* wlr = (const float*)d_in[11];
    const float* blr = (const float*)d_in[12];

    float* out    = (float*)d_out;
    float* mu_out = out;                 // output 0: mu     [32768]
    float* lr_out = out + B_ROWS;        // output 1: out_lr [32768]

    char* ws = (char*)d_ws;
    float2* tab2 = (float2*)ws;                   // 64KB
    bf16x8* w1f  = (bf16x8*)(ws + (64 << 10));    // 64KB
    bf16x8* w2f  = (bf16x8*)(ws + (128 << 10));   // 128KB

    prep<<<NBLK + 48, 256, 0, stream>>>(w1, w2, wt1, bt1, wt2, bt2, tab2, w1f, w2f);
    fused_main<<<B_ROWS / 128, 512, 0, stream>>>(x, w1f, w2f, b1, b2, w3, b3,
                                                 tab2, wlr, blr, mu_out, lr_out);
}